// Round 7
// baseline (6984.583 us; speedup 1.0000x reference)
//
#include <hip/hip_runtime.h>
#include <cmath>

typedef short bfv8 __attribute__((ext_vector_type(8)));   // 8 bf16 as raw shorts
typedef float fv4  __attribute__((ext_vector_type(4)));

#define MFMA_B16(a,b,c) __builtin_amdgcn_mfma_f32_16x16x32_bf16((a),(b),(c),0,0,0)

// fast sigmoid/silu via v_exp_f32 / v_rcp_f32 (~1e-6 rel err)
__device__ __forceinline__ float fast_sigmoid(float x) {
  float e, r;
  asm("v_exp_f32 %0, %1" : "=v"(e) : "v"(-1.442695041f * x));
  const float d = 1.0f + e;
  asm("v_rcp_f32 %0, %1" : "=v"(r) : "v"(d));
  return r;
}
__device__ __forceinline__ float siluf(float x) { return x * fast_sigmoid(x); }

__device__ __forceinline__ unsigned short bf16rne(float x) {
  unsigned u = __float_as_uint(x);
  return (unsigned short)((u + 0x7fffu + ((u >> 16) & 1u)) >> 16);
}
__device__ __forceinline__ float bf2f(unsigned short s) {
  return __uint_as_float(((unsigned)s) << 16);
}

// pack split-bf16: low 16 = hi-part bf16, high 16 = lo-part bf16
__device__ __forceinline__ unsigned packsplit(float v) {
  unsigned uh = __float_as_uint(v) & 0xffff0000u;
  float lof = v - __uint_as_float(uh);
  return (uh >> 16) | (__float_as_uint(lof) & 0xffff0000u);
}

// ---------------------------------------------------------------------------
// Counting sort of edges by row
// ---------------------------------------------------------------------------
__global__ void hist_kernel(const int* __restrict__ eidx, int E,
                            unsigned* __restrict__ cnt)
{
  const int e = blockIdx.x * 256 + threadIdx.x;
  if (e < E) atomicAdd(&cnt[eidx[e]], 1u);
}

__global__ void scan_kernel(const unsigned* __restrict__ cnt,
                            unsigned* __restrict__ cursor, int N)
{
  __shared__ unsigned part[1024];
  const int t = threadIdx.x;
  const int chunk = (N + 1023) / 1024;
  const int base = t * chunk;
  unsigned s = 0;
  for (int i = 0; i < chunk; ++i) {
    const int idx = base + i;
    if (idx < N) s += cnt[idx];
  }
  part[t] = s;
  __syncthreads();
  for (int off = 1; off < 1024; off <<= 1) {
    unsigned v = 0;
    if (t >= off) v = part[t - off];
    __syncthreads();
    if (t >= off) part[t] += v;
    __syncthreads();
  }
  unsigned pre = (t == 0) ? 0u : part[t - 1];
  for (int i = 0; i < chunk; ++i) {
    const int idx = base + i;
    if (idx < N) { cursor[idx] = pre; pre += cnt[idx]; }
  }
}

__global__ void scatter_kernel(const float* __restrict__ x,
                               const int* __restrict__ eidx,
                               const float* __restrict__ eattr, int E,
                               unsigned* __restrict__ cursor,
                               int* __restrict__ sRowA, int* __restrict__ sColA,
                               float* __restrict__ sRadA, float* __restrict__ sEaA,
                               float* __restrict__ sCdA)
{
  const int e = blockIdx.x * 256 + threadIdx.x;
  if (e >= E) return;
  const int r = eidx[e], c = eidx[E + e];
  const float dx = x[(size_t)r * 3 + 0] - x[(size_t)c * 3 + 0];
  const float dy = x[(size_t)r * 3 + 1] - x[(size_t)c * 3 + 1];
  const float dz = x[(size_t)r * 3 + 2] - x[(size_t)c * 3 + 2];
  const float rad = dx * dx + dy * dy + dz * dz;
  const float inv = 1.0f / (sqrtf(rad + 1e-8f) + 1.0f);   // NORM_CONSTANT = 1
  const unsigned pos = atomicAdd(&cursor[r], 1u);
  sRowA[pos] = r;
  sColA[pos] = c;
  sRadA[pos] = rad;
  sEaA[pos]  = eattr[e];
  sCdA[(size_t)pos * 3 + 0] = dx * inv;
  sCdA[(size_t)pos * 3 + 1] = dy * inv;
  sCdA[(size_t)pos * 3 + 2] = dz * inv;
}

// ---------------------------------------------------------------------------
// Dense per-node precompute: Ca = h @ Wa^T + b1, Cb = h @ Wb^T  -> bf16 out
// ---------------------------------------------------------------------------
__global__ __launch_bounds__(256, 3)
void dense2_kernel(const unsigned short* __restrict__ hhi,
                   const unsigned short* __restrict__ hlo, int N,
                   const unsigned short* __restrict__ wh,
                   const unsigned short* __restrict__ wl,
                   const float* __restrict__ b1,
                   unsigned short* __restrict__ Ca, unsigned short* __restrict__ Cb)
{
  const int tid = threadIdx.x;
  const int w = tid >> 6, l = tid & 63;
  const int c16 = l & 15, g = l >> 4;
  const int n0 = blockIdx.x * 128;
  const int rw = w * 32;

#pragma unroll 1
  for (int rt = 0; rt < 2; ++rt) {
    const int nA = min(n0 + rw + rt * 16 + c16, N - 1);
    bfv8 Ah[4], Al[4];
#pragma unroll
    for (int kc = 0; kc < 4; ++kc) {
      const size_t off = (size_t)nA * 128 + kc * 32 + g * 8;
      Ah[kc] = *(const bfv8*)(hhi + off);
      Al[kc] = *(const bfv8*)(hlo + off);
    }
    fv4 accA[8], accB[8];
#pragma unroll
    for (int jt = 0; jt < 8; ++jt) { accA[jt] = (fv4)0.0f; accB[jt] = (fv4)0.0f; }
#pragma unroll 2
    for (int kc = 0; kc < 4; ++kc) {
#pragma unroll
      for (int jt = 0; jt < 8; ++jt) {
        const size_t boA = ((size_t)(kc * 8 + jt) * 64 + l) * 8;
        bfv8 BhA = *(const bfv8*)(wh + boA);
        bfv8 BlA = *(const bfv8*)(wl + boA);
        accA[jt] = MFMA_B16(Ah[kc], BhA, accA[jt]);
        accA[jt] = MFMA_B16(Al[kc], BhA, accA[jt]);
        accA[jt] = MFMA_B16(Ah[kc], BlA, accA[jt]);
        const size_t boB = ((size_t)((kc + 4) * 8 + jt) * 64 + l) * 8;
        bfv8 BhB = *(const bfv8*)(wh + boB);
        bfv8 BlB = *(const bfv8*)(wl + boB);
        accB[jt] = MFMA_B16(Ah[kc], BhB, accB[jt]);
        accB[jt] = MFMA_B16(Al[kc], BhB, accB[jt]);
        accB[jt] = MFMA_B16(Ah[kc], BlB, accB[jt]);
      }
    }
#pragma unroll
    for (int jt = 0; jt < 8; ++jt) {
#pragma unroll
      for (int reg = 0; reg < 4; ++reg) {
        const int n = n0 + rw + rt * 16 + 4 * g + reg;
        if (n < N) {
          const int col = jt * 16 + c16;
          Ca[(size_t)n * 128 + col] = bf16rne(accA[jt][reg] + b1[col]);
          Cb[(size_t)n * 128 + col] = bf16rne(accB[jt][reg]);
        }
      }
    }
  }
}

// ---------------------------------------------------------------------------
// Edge pipeline: H1 = Ca[row]+Cb[col]+rad*t0+ea*t1 (bf16 gathers), silu in
// regs -> GEMM2 A-frags (hi only) -> epilogue -> atomics.
// 256 edges/block, 64/wave as two tile-pairs; B-frags reused across a pair.
// ---------------------------------------------------------------------------
template <int MODE>
__global__ __launch_bounds__(256, 3)
void edge_mfma(const unsigned short* __restrict__ Ca, const unsigned short* __restrict__ Cb,
               const int* __restrict__ sRowA, const int* __restrict__ sColA,
               const float* __restrict__ sRadA, const float* __restrict__ sEaA,
               const float* __restrict__ sCdA, int E,
               const float* __restrict__ W1full,
               const unsigned short* __restrict__ w2h, const unsigned short* __restrict__ w2l,
               const float* __restrict__ b2,
               const float* __restrict__ awv, const float* __restrict__ abv,
               float* __restrict__ outbuf)
{
  __shared__ int    sRow[256], sCol[256];
  __shared__ float  sRad[256], sEa[256];
  __shared__ float2 sT[128];          // (W1[:,256], W1[:,257]) tail columns

  const int tid = threadIdx.x;
  const int w = tid >> 6, l = tid & 63;
  const int c16 = l & 15, g = l >> 4;
  const int e0 = blockIdx.x * 256;

  {
    const int e = min(e0 + tid, E - 1);
    sRow[tid] = sRowA[e];
    sCol[tid] = sColA[e];
    sRad[tid] = sRadA[e];
    sEa[tid]  = sEaA[e];
    if (tid < 128)
      sT[tid] = make_float2(W1full[(size_t)tid * 258 + 256],
                            W1full[(size_t)tid * 258 + 257]);
  }
  __syncthreads();

  const int wb = w * 64;                     // wave's base edge within block
  const float ab0 = (MODE == 0) ? abv[0] : 0.0f;

#pragma unroll 1
  for (int pr = 0; pr < 2; ++pr) {           // tile pair: tiles t0 = 2*pr, t0+1
    const int t0 = pr * 2;
    const int erA = wb + t0 * 16 + c16;      // tile 0 of pair
    const int erB = erA + 16;                // tile 1 of pair

    // ---- issue all 16 gather loads for the pair ----
    bfv8 grA[4], gcA[4], grB[4], gcB[4];
    {
      const int nrA = sRow[erA], ncA = sCol[erA];
      const int nrB = sRow[erB], ncB = sCol[erB];
#pragma unroll
      for (int kc = 0; kc < 4; ++kc) {
        const int j0 = kc * 32 + g * 8;
        grA[kc] = *(const bfv8*)(Ca + (size_t)nrA * 128 + j0);
        gcA[kc] = *(const bfv8*)(Cb + (size_t)ncA * 128 + j0);
        grB[kc] = *(const bfv8*)(Ca + (size_t)nrB * 128 + j0);
        gcB[kc] = *(const bfv8*)(Cb + (size_t)ncB * 128 + j0);
      }
    }

    // ---- convert: H1 sum + silu -> bf16 A-fragments (hi only) ----
    const float radA = sRad[erA], eaA = sEa[erA];
    const float radB = sRad[erB], eaB = sEa[erB];
    bfv8 A0[4], A1[4];
#pragma unroll
    for (int kc = 0; kc < 4; ++kc) {
      const int j0 = kc * 32 + g * 8;
#pragma unroll
      for (int i = 0; i < 8; ++i) {
        const float2 t = sT[j0 + i];
        const float hvA = bf2f((unsigned short)grA[kc][i]) + bf2f((unsigned short)gcA[kc][i])
                          + radA * t.x + eaA * t.y;
        const float hvB = bf2f((unsigned short)grB[kc][i]) + bf2f((unsigned short)gcB[kc][i])
                          + radB * t.x + eaB * t.y;
        A0[kc][i] = (short)bf16rne(siluf(hvA));
        A1[kc][i] = (short)bf16rne(siluf(hvB));
      }
    }

    // ---- GEMM2 for both tiles, B-frags loaded once per (kc,jt) ----
    fv4 acc0[8], acc1[8];
#pragma unroll
    for (int jt = 0; jt < 8; ++jt) { acc0[jt] = (fv4)0.0f; acc1[jt] = (fv4)0.0f; }
#pragma unroll 2
    for (int kc2 = 0; kc2 < 4; ++kc2) {
#pragma unroll
      for (int jt = 0; jt < 8; ++jt) {
        const size_t bo = ((size_t)(kc2 * 8 + jt) * 64 + l) * 8;
        bfv8 Bh = *(const bfv8*)(w2h + bo);
        bfv8 Bl = *(const bfv8*)(w2l + bo);
        acc0[jt] = MFMA_B16(A0[kc2], Bh, acc0[jt]);
        acc0[jt] = MFMA_B16(A0[kc2], Bl, acc0[jt]);
        acc1[jt] = MFMA_B16(A1[kc2], Bh, acc1[jt]);
        acc1[jt] = MFMA_B16(A1[kc2], Bl, acc1[jt]);
      }
    }

    // ---- epilogue per tile ----
#pragma unroll
    for (int tt = 0; tt < 2; ++tt) {
      fv4* acc = tt ? acc1 : acc0;
      float p[4] = {0.f, 0.f, 0.f, 0.f};
#pragma unroll
      for (int jt = 0; jt < 8; ++jt) {
        const int col = jt * 16 + c16;
        const float bb = b2[col], aa = awv[col];
#pragma unroll
        for (int reg = 0; reg < 4; ++reg) {
          const float m = siluf(acc[jt][reg] + bb);
          acc[jt][reg] = m;
          p[reg] += m * aa;
        }
      }
#pragma unroll
      for (int msk = 1; msk < 16; msk <<= 1) {
#pragma unroll
        for (int reg = 0; reg < 4; ++reg) p[reg] += __shfl_xor(p[reg], msk, 64);
      }

      const int base = wb + (t0 + tt) * 16 + 4 * g;   // block-local edge of row reg

      if constexpr (MODE == 0) {
        float att[4];
#pragma unroll
        for (int reg = 0; reg < 4; ++reg) {
          const float a = fast_sigmoid(p[reg] + ab0);
          att[reg] = (e0 + base + reg < E) ? a : 0.0f;
        }
#pragma unroll
        for (int jt = 0; jt < 8; ++jt) {
          const int col = jt * 16 + c16;
#pragma unroll
          for (int reg = 0; reg < 4; ++reg) {
            unsafeAtomicAdd(outbuf + (size_t)sRow[base + reg] * 128 + col,
                            acc[jt][reg] * att[reg]);
          }
        }
      } else {
        if (c16 < 3) {
          const int cx = c16;
#pragma unroll
          for (int reg = 0; reg < 4; ++reg) {
            const int e = min(e0 + base + reg, E - 1);
            const float s = (e0 + base + reg < E) ? p[reg] * 0.01f : 0.0f;
            unsafeAtomicAdd(outbuf + (size_t)sRow[base + reg] * 3 + cx,
                            sCdA[(size_t)e * 3 + cx] * s);
          }
        }
      }
    }
  }
}

// ---------------------------------------------------------------------------
// Node model (MFMA): msg = silu([h, agg/100] W1^T + b1) W2^T + b2; h += msg
// Emits updated split-bf16 planes (fused split).
// ---------------------------------------------------------------------------
__global__ __launch_bounds__(256, 3)
void node_mfma(float* __restrict__ hio,
               const unsigned short* __restrict__ hhi,
               const unsigned short* __restrict__ hlo,
               unsigned short* __restrict__ ohi,
               unsigned short* __restrict__ olo,
               const float* __restrict__ agg, int N,
               const unsigned short* __restrict__ w1h, const unsigned short* __restrict__ w1l,
               const float* __restrict__ b1,
               const unsigned short* __restrict__ w2h, const unsigned short* __restrict__ w2l,
               const float* __restrict__ b2)
{
  __shared__ __align__(16) unsigned sH[4][2048];

  const int tid = threadIdx.x;
  const int w = tid >> 6, l = tid & 63;
  const int c16 = l & 15, g = l >> 4;
  const int n0 = blockIdx.x * 128;
  const int rw = w * 32;

  int rowA[2];
#pragma unroll
  for (int rt = 0; rt < 2; ++rt) rowA[rt] = min(n0 + rw + rt * 16 + c16, N - 1);

  fv4 acc[2][8];
#pragma unroll
  for (int a = 0; a < 2; ++a)
#pragma unroll
    for (int b = 0; b < 8; ++b) acc[a][b] = (fv4)0.0f;

#pragma unroll 2
  for (int kc = 0; kc < 8; ++kc) {
    bfv8 Ah[2], Al[2];
    if (kc < 4) {
      const int kh = kc * 32 + g * 8;
#pragma unroll
      for (int rt = 0; rt < 2; ++rt) {
        const size_t off = (size_t)rowA[rt] * 128 + kh;
        Ah[rt] = *(const bfv8*)(hhi + off);
        Al[rt] = *(const bfv8*)(hlo + off);
      }
    } else {
      const int kh = (kc - 4) * 32 + g * 8;
#pragma unroll
      for (int rt = 0; rt < 2; ++rt) {
        const float4 v0 = *(const float4*)(agg + (size_t)rowA[rt] * 128 + kh);
        const float4 v1 = *(const float4*)(agg + (size_t)rowA[rt] * 128 + kh + 4);
        const float vv[8] = {v0.x, v0.y, v0.z, v0.w, v1.x, v1.y, v1.z, v1.w};
#pragma unroll
        for (int i = 0; i < 8; ++i) {
          const float xs = vv[i] * 0.01f;            // agg / normalization_factor
          const unsigned uh = __float_as_uint(xs) & 0xffff0000u;
          Ah[rt][i] = (short)(uh >> 16);
          const float lof = xs - __uint_as_float(uh);
          Al[rt][i] = (short)(__float_as_uint(lof) >> 16);
        }
      }
    }
#pragma unroll
    for (int jt = 0; jt < 8; ++jt) {
      const size_t bo = ((size_t)(kc * 8 + jt) * 64 + l) * 8;
      bfv8 Bh = *(const bfv8*)(w1h + bo);
      bfv8 Bl = *(const bfv8*)(w1l + bo);
#pragma unroll
      for (int rt = 0; rt < 2; ++rt) {
        acc[rt][jt] = MFMA_B16(Ah[rt], Bh, acc[rt][jt]);
        acc[rt][jt] = MFMA_B16(Al[rt], Bh, acc[rt][jt]);
        acc[rt][jt] = MFMA_B16(Ah[rt], Bl, acc[rt][jt]);
      }
    }
  }

  unsigned* sHW = sH[w];
#pragma unroll 1
  for (int rt = 0; rt < 2; ++rt) {
#pragma unroll
    for (int jt = 0; jt < 8; ++jt) {
      const int col = jt * 16 + c16;
      const float bb = b1[col];
#pragma unroll
      for (int reg = 0; reg < 4; ++reg) {
        const int rr = 4 * g + reg;
        sHW[rr * 128 + (col ^ ((rr & 7) << 2))] = packsplit(siluf(acc[rt][jt][reg] + bb));
      }
    }

    fv4 accB[8];
#pragma unroll
    for (int jt = 0; jt < 8; ++jt) accB[jt] = (fv4)0.0f;
    const int sxz = (c16 & 7) << 2;
#pragma unroll 2
    for (int kc2 = 0; kc2 < 4; ++kc2) {
      const int k0 = kc2 * 32 + g * 8;
      const int i1 = c16 * 128 + (k0 ^ sxz);
      const int4 q0 = *((const int4*)(sHW + i1));
      const int4 q1 = *((const int4*)(sHW + (i1 ^ 4)));
      bfv8 Ah2, Al2;
      {
        const int qq[8] = {q0.x, q0.y, q0.z, q0.w, q1.x, q1.y, q1.z, q1.w};
#pragma unroll
        for (int i = 0; i < 8; ++i) {
          Ah2[i] = (short)(((unsigned)qq[i]) & 0xffffu);
          Al2[i] = (short)(((unsigned)qq[i]) >> 16);
        }
      }
#pragma unroll
      for (int jt = 0; jt < 8; ++jt) {
        const size_t bo = ((size_t)(kc2 * 8 + jt) * 64 + l) * 8;
        bfv8 Bh = *(const bfv8*)(w2h + bo);
        bfv8 Bl = *(const bfv8*)(w2l + bo);
        accB[jt] = MFMA_B16(Ah2, Bh, accB[jt]);
        accB[jt] = MFMA_B16(Al2, Bh, accB[jt]);
        accB[jt] = MFMA_B16(Ah2, Bl, accB[jt]);
      }
    }

#pragma unroll
    for (int reg = 0; reg < 4; ++reg) {
      const int n = n0 + rw + rt * 16 + 4 * g + reg;
      if (n < N) {
        float* hp = hio + (size_t)n * 128;
#pragma unroll
        for (int jt = 0; jt < 8; ++jt) {
          const int col = jt * 16 + c16;
          const float nv = hp[col] + accB[jt][reg] + b2[col];   // residual add
          hp[col] = nv;
          const unsigned ps = packsplit(nv);
          ohi[(size_t)n * 128 + col] = (unsigned short)(ps & 0xffffu);
          olo[(size_t)n * 128 + col] = (unsigned short)(ps >> 16);
        }
      }
    }
  }
}

// split fp32 -> bf16 hi/lo planes — initial h only
__global__ void split_kernel(const float* __restrict__ src,
                             unsigned short* __restrict__ hi,
                             unsigned short* __restrict__ lo, int n4)
{
  const int i = blockIdx.x * 256 + threadIdx.x;
  if (i >= n4) return;
  const float4 v = ((const float4*)src)[i];
  const float vv[4] = {v.x, v.y, v.z, v.w};
  ushort4 ho, lq;
  unsigned short* hp = (unsigned short*)&ho;
  unsigned short* lp = (unsigned short*)&lq;
#pragma unroll
  for (int k = 0; k < 4; ++k) {
    const unsigned uh = __float_as_uint(vv[k]) & 0xffff0000u;
    hp[k] = (unsigned short)(uh >> 16);
    const float lof = vv[k] - __uint_as_float(uh);
    lp[k] = (unsigned short)(__float_as_uint(lof) >> 16);
  }
  ((ushort4*)hi)[i] = ho;
  ((ushort4*)lo)[i] = lq;
}

// weight prep: W[j][k] (row-major, stride SW) -> MFMA B-frag layout hi/lo planes
struct WDesc { const float* src; unsigned short* hi; unsigned short* lo; int K; int SW; };
struct WAll { WDesc m[10]; };

__global__ void wprep_kernel(WAll wa)
{
  const WDesc d = wa.m[blockIdx.y];
  const int idx = blockIdx.x * 256 + threadIdx.x;
  const int j = idx & 127, k = idx >> 7;
  if (k >= d.K) return;
  const float v = d.src[(size_t)j * d.SW + k];
  const unsigned uh = __float_as_uint(v) & 0xffff0000u;
  const float lof = v - __uint_as_float(uh);
  // frag index: [ktile][jtile][lane=g*16+c][8]
  const int fo = ((((k >> 5) * 8 + (j >> 4)) * 64) + ((k >> 3) & 3) * 16 + (j & 15)) * 8 + (k & 7);
  d.hi[fo] = (unsigned short)(uh >> 16);
  d.lo[fo] = (unsigned short)(__float_as_uint(lof) >> 16);
}

extern "C" void kernel_launch(void* const* d_in, const int* in_sizes, int n_in,
                              void* d_out, int out_size, void* d_ws, size_t ws_size,
                              hipStream_t stream)
{
  const float* h_in  = (const float*)d_in[0];
  const float* x_in  = (const float*)d_in[1];
  const float* eattr = (const float*)d_in[2];
  const int*   eidx  = (const int*)d_in[3];
  const int N = in_sizes[0] / 128;
  const int E = in_sizes[2];

  const float* P[25];
  for (int i = 0; i < 25; ++i) P[i] = (const float*)d_in[4 + i];

  float* h_out = (float*)d_out;                     // [N,128]
  float* x_out = (float*)d_out + (size_t)N * 128;   // [N,3]

  // workspace carve
  float*    agg    = (float*)d_ws;                          // [N,128]
  unsigned* cnt    = (unsigned*)(agg + (size_t)N * 128);    // [N]
  unsigned* cursor = cnt + N;                               // [N]
  int*      sRowA  = (int*)(cursor + N);                    // [E]
  int*      sColA  = sRowA + E;                             // [E]
  float*    sRadA  = (float*)(sColA + E);                   // [E]
  float*    sEaA   = sRadA + E;                             // [E]
  float*    sCdA   = sEaA + E;                              // [E,3]
  unsigned short* hhi = (unsigned short*)(sCdA + (size_t)3 * E);  // [N,128]
  unsigned short* hlo = hhi + (size_t)N * 128;              // [N,128]
  unsigned short* wptr = hlo + (size_t)N * 128;

  WAll wa;
  auto addw = [&](int slot, const float* s, int K, int SW) {
    wa.m[slot].src = s; wa.m[slot].hi = wptr; wa.m[slot].lo = wptr + (size_t)K * 128;
    wa.m[slot].K = K; wa.m[slot].SW = SW;
    wptr += (size_t)2 * K * 128;
  };
  addw(0, P[0], 256, 258);  addw(1, P[2], 128, 128);   // g0 ew1, ew2
  addw(2, P[6], 256, 256);  addw(3, P[8], 128, 128);   // g0 nw1, nw2
  addw(4, P[10], 256, 258); addw(5, P[12], 128, 128);  // g1 ew1, ew2
  addw(6, P[16], 256, 256); addw(7, P[18], 128, 128);  // g1 nw1, nw2
  addw(8, P[20], 256, 258); addw(9, P[22], 128, 128);  // eq w1, w2

  unsigned short* Ca = wptr;                                // [N,128] bf16
  unsigned short* Cb = Ca + (size_t)N * 128;                // [N,128] bf16

  hipMemcpyAsync(h_out, h_in, (size_t)N * 128 * sizeof(float),
                 hipMemcpyDeviceToDevice, stream);
  hipMemcpyAsync(x_out, x_in, (size_t)N * 3 * sizeof(float),
                 hipMemcpyDeviceToDevice, stream);

  // sort edges by row; radial/coord_diff computed during scatter
  hipMemsetAsync(cnt, 0, (size_t)N * sizeof(unsigned), stream);
  hist_kernel<<<(E + 255) / 256, 256, 0, stream>>>(eidx, E, cnt);
  scan_kernel<<<1, 1024, 0, stream>>>(cnt, cursor, N);
  scatter_kernel<<<(E + 255) / 256, 256, 0, stream>>>(x_in, eidx, eattr, E,
      cursor, sRowA, sColA, sRadA, sEaA, sCdA);

  wprep_kernel<<<dim3(128, 10), 256, 0, stream>>>(wa);

  const int n4 = N * 32;                 // N*128/4
  const int sg = (n4 + 255) / 256;
  const int eg = (E + 255) / 256;        // 256 edges per block now
  const int ng = (N + 127) / 128;

  split_kernel<<<sg, 256, 0, stream>>>(h_out, hhi, hlo, n4);

  for (int lyr = 0; lyr < 2; ++lyr) {
    const float* const* G = P + 10 * lyr;
    const WDesc* M = &wa.m[4 * lyr];
    dense2_kernel<<<ng, 256, 0, stream>>>(hhi, hlo, N, M[0].hi, M[0].lo, G[1], Ca, Cb);
    hipMemsetAsync(agg, 0, (size_t)N * 128 * sizeof(float), stream);
    edge_mfma<0><<<eg, 256, 0, stream>>>(Ca, Cb, sRowA, sColA, sRadA, sEaA, sCdA, E,
        G[0], M[1].hi, M[1].lo, G[3], G[4], G[5], agg);
    node_mfma<<<ng, 256, 0, stream>>>(h_out, hhi, hlo, hhi, hlo, agg, N,
        M[2].hi, M[2].lo, G[7], M[3].hi, M[3].lo, G[9]);
  }

  dense2_kernel<<<ng, 256, 0, stream>>>(hhi, hlo, N, wa.m[8].hi, wa.m[8].lo, P[21], Ca, Cb);
  edge_mfma<1><<<eg, 256, 0, stream>>>(Ca, Cb, sRowA, sColA, sRadA, sEaA, sCdA, E,
      P[20], wa.m[9].hi, wa.m[9].lo, P[23], P[24], nullptr, x_out);
}

// Round 8
// 6983.795 us; speedup vs baseline: 1.0001x; 1.0001x over previous
//
#include <hip/hip_runtime.h>
#include <cmath>

typedef short bfv8 __attribute__((ext_vector_type(8)));   // 8 bf16 as raw shorts
typedef float fv4  __attribute__((ext_vector_type(4)));

#define MFMA_B16(a,b,c) __builtin_amdgcn_mfma_f32_16x16x32_bf16((a),(b),(c),0,0,0)

// fast sigmoid/silu via v_exp_f32 / v_rcp_f32 (~1e-6 rel err)
__device__ __forceinline__ float fast_sigmoid(float x) {
  float e, r;
  asm("v_exp_f32 %0, %1" : "=v"(e) : "v"(-1.442695041f * x));
  const float d = 1.0f + e;
  asm("v_rcp_f32 %0, %1" : "=v"(r) : "v"(d));
  return r;
}
__device__ __forceinline__ float siluf(float x) { return x * fast_sigmoid(x); }

__device__ __forceinline__ unsigned short bf16rne(float x) {
  unsigned u = __float_as_uint(x);
  return (unsigned short)((u + 0x7fffu + ((u >> 16) & 1u)) >> 16);
}
__device__ __forceinline__ float bf2f(unsigned short s) {
  return __uint_as_float(((unsigned)s) << 16);
}

// pack split-bf16: low 16 = hi-part bf16, high 16 = lo-part bf16
__device__ __forceinline__ unsigned packsplit(float v) {
  unsigned uh = __float_as_uint(v) & 0xffff0000u;
  float lof = v - __uint_as_float(uh);
  return (uh >> 16) | (__float_as_uint(lof) & 0xffff0000u);
}

// ---------------------------------------------------------------------------
// Counting sort of edges by row
// ---------------------------------------------------------------------------
__global__ void hist_kernel(const int* __restrict__ eidx, int E,
                            unsigned* __restrict__ cnt)
{
  const int e = blockIdx.x * 256 + threadIdx.x;
  if (e < E) atomicAdd(&cnt[eidx[e]], 1u);
}

__global__ void scan_kernel(const unsigned* __restrict__ cnt,
                            unsigned* __restrict__ cursor, int N)
{
  __shared__ unsigned part[1024];
  const int t = threadIdx.x;
  const int chunk = (N + 1023) / 1024;
  const int base = t * chunk;
  unsigned s = 0;
  for (int i = 0; i < chunk; ++i) {
    const int idx = base + i;
    if (idx < N) s += cnt[idx];
  }
  part[t] = s;
  __syncthreads();
  for (int off = 1; off < 1024; off <<= 1) {
    unsigned v = 0;
    if (t >= off) v = part[t - off];
    __syncthreads();
    if (t >= off) part[t] += v;
    __syncthreads();
  }
  unsigned pre = (t == 0) ? 0u : part[t - 1];
  for (int i = 0; i < chunk; ++i) {
    const int idx = base + i;
    if (idx < N) { cursor[idx] = pre; pre += cnt[idx]; }
  }
}

__global__ void scatter_kernel(const float* __restrict__ x,
                               const int* __restrict__ eidx,
                               const float* __restrict__ eattr, int E,
                               unsigned* __restrict__ cursor,
                               int* __restrict__ sRowA, int* __restrict__ sColA,
                               float* __restrict__ sRadA, float* __restrict__ sEaA,
                               float* __restrict__ sCdA)
{
  const int e = blockIdx.x * 256 + threadIdx.x;
  if (e >= E) return;
  const int r = eidx[e], c = eidx[E + e];
  const float dx = x[(size_t)r * 3 + 0] - x[(size_t)c * 3 + 0];
  const float dy = x[(size_t)r * 3 + 1] - x[(size_t)c * 3 + 1];
  const float dz = x[(size_t)r * 3 + 2] - x[(size_t)c * 3 + 2];
  const float rad = dx * dx + dy * dy + dz * dz;
  const float inv = 1.0f / (sqrtf(rad + 1e-8f) + 1.0f);   // NORM_CONSTANT = 1
  const unsigned pos = atomicAdd(&cursor[r], 1u);
  sRowA[pos] = r;
  sColA[pos] = c;
  sRadA[pos] = rad;
  sEaA[pos]  = eattr[e];
  sCdA[(size_t)pos * 3 + 0] = dx * inv;
  sCdA[(size_t)pos * 3 + 1] = dy * inv;
  sCdA[(size_t)pos * 3 + 2] = dz * inv;
}

// ---------------------------------------------------------------------------
// Dense per-node precompute: Ca = h @ Wa^T + b1, Cb = h @ Wb^T  -> bf16 out
// ---------------------------------------------------------------------------
__global__ __launch_bounds__(256, 3)
void dense2_kernel(const unsigned short* __restrict__ hhi,
                   const unsigned short* __restrict__ hlo, int N,
                   const unsigned short* __restrict__ wh,
                   const unsigned short* __restrict__ wl,
                   const float* __restrict__ b1,
                   unsigned short* __restrict__ Ca, unsigned short* __restrict__ Cb)
{
  const int tid = threadIdx.x;
  const int w = tid >> 6, l = tid & 63;
  const int c16 = l & 15, g = l >> 4;
  const int n0 = blockIdx.x * 128;
  const int rw = w * 32;

#pragma unroll 1
  for (int rt = 0; rt < 2; ++rt) {
    const int nA = min(n0 + rw + rt * 16 + c16, N - 1);
    bfv8 Ah[4], Al[4];
#pragma unroll
    for (int kc = 0; kc < 4; ++kc) {
      const size_t off = (size_t)nA * 128 + kc * 32 + g * 8;
      Ah[kc] = *(const bfv8*)(hhi + off);
      Al[kc] = *(const bfv8*)(hlo + off);
    }
    fv4 accA[8], accB[8];
#pragma unroll
    for (int jt = 0; jt < 8; ++jt) { accA[jt] = (fv4)0.0f; accB[jt] = (fv4)0.0f; }
#pragma unroll 2
    for (int kc = 0; kc < 4; ++kc) {
#pragma unroll
      for (int jt = 0; jt < 8; ++jt) {
        const size_t boA = ((size_t)(kc * 8 + jt) * 64 + l) * 8;
        bfv8 BhA = *(const bfv8*)(wh + boA);
        bfv8 BlA = *(const bfv8*)(wl + boA);
        accA[jt] = MFMA_B16(Ah[kc], BhA, accA[jt]);
        accA[jt] = MFMA_B16(Al[kc], BhA, accA[jt]);
        accA[jt] = MFMA_B16(Ah[kc], BlA, accA[jt]);
        const size_t boB = ((size_t)((kc + 4) * 8 + jt) * 64 + l) * 8;
        bfv8 BhB = *(const bfv8*)(wh + boB);
        bfv8 BlB = *(const bfv8*)(wl + boB);
        accB[jt] = MFMA_B16(Ah[kc], BhB, accB[jt]);
        accB[jt] = MFMA_B16(Al[kc], BhB, accB[jt]);
        accB[jt] = MFMA_B16(Ah[kc], BlB, accB[jt]);
      }
    }
#pragma unroll
    for (int jt = 0; jt < 8; ++jt) {
#pragma unroll
      for (int reg = 0; reg < 4; ++reg) {
        const int n = n0 + rw + rt * 16 + 4 * g + reg;
        if (n < N) {
          const int col = jt * 16 + c16;
          Ca[(size_t)n * 128 + col] = bf16rne(accA[jt][reg] + b1[col]);
          Cb[(size_t)n * 128 + col] = bf16rne(accB[jt][reg]);
        }
      }
    }
  }
}

// ---------------------------------------------------------------------------
// Edge pipeline: H1 = Ca[row]+Cb[col]+rad*t0+ea*t1 (bf16 gathers), silu in
// regs -> GEMM2 A-frags (hi only) -> epilogue -> atomics.
// 256 edges/block, 64/wave as two tile-pairs; B-frags reused across a pair.
// Epilogue is a MACRO (rule #20: a runtime fv4* into acc0/acc1 forces the
// accumulators to scratch -> 6.4 GB spill traffic in round 7. Never again.)
// ---------------------------------------------------------------------------
#define EDGE_EPILOGUE(ACC, TT)                                                  \
  {                                                                             \
    float p[4] = {0.f, 0.f, 0.f, 0.f};                                          \
    _Pragma("unroll")                                                           \
    for (int jt = 0; jt < 8; ++jt) {                                            \
      const int col = jt * 16 + c16;                                            \
      const float bb = b2[col], aa = awv[col];                                  \
      _Pragma("unroll")                                                         \
      for (int reg = 0; reg < 4; ++reg) {                                       \
        const float m = siluf(ACC[jt][reg] + bb);                               \
        ACC[jt][reg] = m;                                                       \
        p[reg] += m * aa;                                                       \
      }                                                                         \
    }                                                                           \
    _Pragma("unroll")                                                           \
    for (int msk = 1; msk < 16; msk <<= 1) {                                    \
      _Pragma("unroll")                                                         \
      for (int reg = 0; reg < 4; ++reg) p[reg] += __shfl_xor(p[reg], msk, 64);  \
    }                                                                           \
    const int base = wb + (t0 + (TT)) * 16 + 4 * g;                             \
    if constexpr (MODE == 0) {                                                  \
      float att[4];                                                             \
      _Pragma("unroll")                                                         \
      for (int reg = 0; reg < 4; ++reg) {                                       \
        const float a = fast_sigmoid(p[reg] + ab0);                             \
        att[reg] = (e0 + base + reg < E) ? a : 0.0f;                            \
      }                                                                         \
      _Pragma("unroll")                                                         \
      for (int jt = 0; jt < 8; ++jt) {                                          \
        const int col = jt * 16 + c16;                                          \
        _Pragma("unroll")                                                       \
        for (int reg = 0; reg < 4; ++reg) {                                     \
          unsafeAtomicAdd(outbuf + (size_t)sRow[base + reg] * 128 + col,        \
                          ACC[jt][reg] * att[reg]);                             \
        }                                                                       \
      }                                                                         \
    } else {                                                                    \
      if (c16 < 3) {                                                            \
        const int cx = c16;                                                     \
        _Pragma("unroll")                                                       \
        for (int reg = 0; reg < 4; ++reg) {                                     \
          const int e = min(e0 + base + reg, E - 1);                            \
          const float s = (e0 + base + reg < E) ? p[reg] * 0.01f : 0.0f;        \
          unsafeAtomicAdd(outbuf + (size_t)sRow[base + reg] * 3 + cx,           \
                          sCdA[(size_t)e * 3 + cx] * s);                        \
        }                                                                       \
      }                                                                         \
    }                                                                           \
  }

template <int MODE>
__global__ __launch_bounds__(256, 3)
void edge_mfma(const unsigned short* __restrict__ Ca, const unsigned short* __restrict__ Cb,
               const int* __restrict__ sRowA, const int* __restrict__ sColA,
               const float* __restrict__ sRadA, const float* __restrict__ sEaA,
               const float* __restrict__ sCdA, int E,
               const float* __restrict__ W1full,
               const unsigned short* __restrict__ w2h, const unsigned short* __restrict__ w2l,
               const float* __restrict__ b2,
               const float* __restrict__ awv, const float* __restrict__ abv,
               float* __restrict__ outbuf)
{
  __shared__ int    sRow[256], sCol[256];
  __shared__ float  sRad[256], sEa[256];
  __shared__ float2 sT[128];          // (W1[:,256], W1[:,257]) tail columns

  const int tid = threadIdx.x;
  const int w = tid >> 6, l = tid & 63;
  const int c16 = l & 15, g = l >> 4;
  const int e0 = blockIdx.x * 256;

  {
    const int e = min(e0 + tid, E - 1);
    sRow[tid] = sRowA[e];
    sCol[tid] = sColA[e];
    sRad[tid] = sRadA[e];
    sEa[tid]  = sEaA[e];
    if (tid < 128)
      sT[tid] = make_float2(W1full[(size_t)tid * 258 + 256],
                            W1full[(size_t)tid * 258 + 257]);
  }
  __syncthreads();

  const int wb = w * 64;                     // wave's base edge within block
  const float ab0 = (MODE == 0) ? abv[0] : 0.0f;

#pragma unroll 1
  for (int pr = 0; pr < 2; ++pr) {           // tile pair: tiles t0 = 2*pr, t0+1
    const int t0 = pr * 2;
    const int erA = wb + t0 * 16 + c16;      // tile 0 of pair
    const int erB = erA + 16;                // tile 1 of pair

    // ---- issue all 16 gather loads for the pair ----
    bfv8 grA[4], gcA[4], grB[4], gcB[4];
    {
      const int nrA = sRow[erA], ncA = sCol[erA];
      const int nrB = sRow[erB], ncB = sCol[erB];
#pragma unroll
      for (int kc = 0; kc < 4; ++kc) {
        const int j0 = kc * 32 + g * 8;
        grA[kc] = *(const bfv8*)(Ca + (size_t)nrA * 128 + j0);
        gcA[kc] = *(const bfv8*)(Cb + (size_t)ncA * 128 + j0);
        grB[kc] = *(const bfv8*)(Ca + (size_t)nrB * 128 + j0);
        gcB[kc] = *(const bfv8*)(Cb + (size_t)ncB * 128 + j0);
      }
    }

    // ---- convert: H1 sum + silu -> bf16 A-fragments (hi only) ----
    const float radA = sRad[erA], eaA = sEa[erA];
    const float radB = sRad[erB], eaB = sEa[erB];
    bfv8 A0[4], A1[4];
#pragma unroll
    for (int kc = 0; kc < 4; ++kc) {
      const int j0 = kc * 32 + g * 8;
#pragma unroll
      for (int i = 0; i < 8; ++i) {
        const float2 t = sT[j0 + i];
        const float hvA = bf2f((unsigned short)grA[kc][i]) + bf2f((unsigned short)gcA[kc][i])
                          + radA * t.x + eaA * t.y;
        const float hvB = bf2f((unsigned short)grB[kc][i]) + bf2f((unsigned short)gcB[kc][i])
                          + radB * t.x + eaB * t.y;
        A0[kc][i] = (short)bf16rne(siluf(hvA));
        A1[kc][i] = (short)bf16rne(siluf(hvB));
      }
    }

    // ---- GEMM2 for both tiles, B-frags loaded once per (kc,jt) ----
    fv4 acc0[8], acc1[8];
#pragma unroll
    for (int jt = 0; jt < 8; ++jt) { acc0[jt] = (fv4)0.0f; acc1[jt] = (fv4)0.0f; }
#pragma unroll 2
    for (int kc2 = 0; kc2 < 4; ++kc2) {
#pragma unroll
      for (int jt = 0; jt < 8; ++jt) {
        const size_t bo = ((size_t)(kc2 * 8 + jt) * 64 + l) * 8;
        bfv8 Bh = *(const bfv8*)(w2h + bo);
        bfv8 Bl = *(const bfv8*)(w2l + bo);
        acc0[jt] = MFMA_B16(A0[kc2], Bh, acc0[jt]);
        acc0[jt] = MFMA_B16(A0[kc2], Bl, acc0[jt]);
        acc1[jt] = MFMA_B16(A1[kc2], Bh, acc1[jt]);
        acc1[jt] = MFMA_B16(A1[kc2], Bl, acc1[jt]);
      }
    }

    // ---- epilogues: statically expanded per accumulator (no reg-array ptr) ----
    EDGE_EPILOGUE(acc0, 0)
    EDGE_EPILOGUE(acc1, 1)
  }
}

// ---------------------------------------------------------------------------
// Node model (MFMA): msg = silu([h, agg/100] W1^T + b1) W2^T + b2; h += msg
// Emits updated split-bf16 planes (fused split).
// ---------------------------------------------------------------------------
__global__ __launch_bounds__(256, 3)
void node_mfma(float* __restrict__ hio,
               const unsigned short* __restrict__ hhi,
               const unsigned short* __restrict__ hlo,
               unsigned short* __restrict__ ohi,
               unsigned short* __restrict__ olo,
               const float* __restrict__ agg, int N,
               const unsigned short* __restrict__ w1h, const unsigned short* __restrict__ w1l,
               const float* __restrict__ b1,
               const unsigned short* __restrict__ w2h, const unsigned short* __restrict__ w2l,
               const float* __restrict__ b2)
{
  __shared__ __align__(16) unsigned sH[4][2048];

  const int tid = threadIdx.x;
  const int w = tid >> 6, l = tid & 63;
  const int c16 = l & 15, g = l >> 4;
  const int n0 = blockIdx.x * 128;
  const int rw = w * 32;

  int rowA[2];
#pragma unroll
  for (int rt = 0; rt < 2; ++rt) rowA[rt] = min(n0 + rw + rt * 16 + c16, N - 1);

  fv4 acc[2][8];
#pragma unroll
  for (int a = 0; a < 2; ++a)
#pragma unroll
    for (int b = 0; b < 8; ++b) acc[a][b] = (fv4)0.0f;

#pragma unroll 2
  for (int kc = 0; kc < 8; ++kc) {
    bfv8 Ah[2], Al[2];
    if (kc < 4) {
      const int kh = kc * 32 + g * 8;
#pragma unroll
      for (int rt = 0; rt < 2; ++rt) {
        const size_t off = (size_t)rowA[rt] * 128 + kh;
        Ah[rt] = *(const bfv8*)(hhi + off);
        Al[rt] = *(const bfv8*)(hlo + off);
      }
    } else {
      const int kh = (kc - 4) * 32 + g * 8;
#pragma unroll
      for (int rt = 0; rt < 2; ++rt) {
        const float4 v0 = *(const float4*)(agg + (size_t)rowA[rt] * 128 + kh);
        const float4 v1 = *(const float4*)(agg + (size_t)rowA[rt] * 128 + kh + 4);
        const float vv[8] = {v0.x, v0.y, v0.z, v0.w, v1.x, v1.y, v1.z, v1.w};
#pragma unroll
        for (int i = 0; i < 8; ++i) {
          const float xs = vv[i] * 0.01f;            // agg / normalization_factor
          const unsigned uh = __float_as_uint(xs) & 0xffff0000u;
          Ah[rt][i] = (short)(uh >> 16);
          const float lof = xs - __uint_as_float(uh);
          Al[rt][i] = (short)(__float_as_uint(lof) >> 16);
        }
      }
    }
#pragma unroll
    for (int jt = 0; jt < 8; ++jt) {
      const size_t bo = ((size_t)(kc * 8 + jt) * 64 + l) * 8;
      bfv8 Bh = *(const bfv8*)(w1h + bo);
      bfv8 Bl = *(const bfv8*)(w1l + bo);
#pragma unroll
      for (int rt = 0; rt < 2; ++rt) {
        acc[rt][jt] = MFMA_B16(Ah[rt], Bh, acc[rt][jt]);
        acc[rt][jt] = MFMA_B16(Al[rt], Bh, acc[rt][jt]);
        acc[rt][jt] = MFMA_B16(Ah[rt], Bl, acc[rt][jt]);
      }
    }
  }

  unsigned* sHW = sH[w];
#pragma unroll 1
  for (int rt = 0; rt < 2; ++rt) {
#pragma unroll
    for (int jt = 0; jt < 8; ++jt) {
      const int col = jt * 16 + c16;
      const float bb = b1[col];
#pragma unroll
      for (int reg = 0; reg < 4; ++reg) {
        const int rr = 4 * g + reg;
        sHW[rr * 128 + (col ^ ((rr & 7) << 2))] = packsplit(siluf(acc[rt][jt][reg] + bb));
      }
    }

    fv4 accB[8];
#pragma unroll
    for (int jt = 0; jt < 8; ++jt) accB[jt] = (fv4)0.0f;
    const int sxz = (c16 & 7) << 2;
#pragma unroll 2
    for (int kc2 = 0; kc2 < 4; ++kc2) {
      const int k0 = kc2 * 32 + g * 8;
      const int i1 = c16 * 128 + (k0 ^ sxz);
      const int4 q0 = *((const int4*)(sHW + i1));
      const int4 q1 = *((const int4*)(sHW + (i1 ^ 4)));
      bfv8 Ah2, Al2;
      {
        const int qq[8] = {q0.x, q0.y, q0.z, q0.w, q1.x, q1.y, q1.z, q1.w};
#pragma unroll
        for (int i = 0; i < 8; ++i) {
          Ah2[i] = (short)(((unsigned)qq[i]) & 0xffffu);
          Al2[i] = (short)(((unsigned)qq[i]) >> 16);
        }
      }
#pragma unroll
      for (int jt = 0; jt < 8; ++jt) {
        const size_t bo = ((size_t)(kc2 * 8 + jt) * 64 + l) * 8;
        bfv8 Bh = *(const bfv8*)(w2h + bo);
        bfv8 Bl = *(const bfv8*)(w2l + bo);
        accB[jt] = MFMA_B16(Ah2, Bh, accB[jt]);
        accB[jt] = MFMA_B16(Al2, Bh, accB[jt]);
        accB[jt] = MFMA_B16(Ah2, Bl, accB[jt]);
      }
    }

#pragma unroll
    for (int reg = 0; reg < 4; ++reg) {
      const int n = n0 + rw + rt * 16 + 4 * g + reg;
      if (n < N) {
        float* hp = hio + (size_t)n * 128;
#pragma unroll
        for (int jt = 0; jt < 8; ++jt) {
          const int col = jt * 16 + c16;
          const float nv = hp[col] + accB[jt][reg] + b2[col];   // residual add
          hp[col] = nv;
          const unsigned ps = packsplit(nv);
          ohi[(size_t)n * 128 + col] = (unsigned short)(ps & 0xffffu);
          olo[(size_t)n * 128 + col] = (unsigned short)(ps >> 16);
        }
      }
    }
  }
}

// split fp32 -> bf16 hi/lo planes — initial h only
__global__ void split_kernel(const float* __restrict__ src,
                             unsigned short* __restrict__ hi,
                             unsigned short* __restrict__ lo, int n4)
{
  const int i = blockIdx.x * 256 + threadIdx.x;
  if (i >= n4) return;
  const float4 v = ((const float4*)src)[i];
  const float vv[4] = {v.x, v.y, v.z, v.w};
  ushort4 ho, lq;
  unsigned short* hp = (unsigned short*)&ho;
  unsigned short* lp = (unsigned short*)&lq;
#pragma unroll
  for (int k = 0; k < 4; ++k) {
    const unsigned uh = __float_as_uint(vv[k]) & 0xffff0000u;
    hp[k] = (unsigned short)(uh >> 16);
    const float lof = vv[k] - __uint_as_float(uh);
    lp[k] = (unsigned short)(__float_as_uint(lof) >> 16);
  }
  ((ushort4*)hi)[i] = ho;
  ((ushort4*)lo)[i] = lq;
}

// weight prep: W[j][k] (row-major, stride SW) -> MFMA B-frag layout hi/lo planes
struct WDesc { const float* src; unsigned short* hi; unsigned short* lo; int K; int SW; };
struct WAll { WDesc m[10]; };

__global__ void wprep_kernel(WAll wa)
{
  const WDesc d = wa.m[blockIdx.y];
  const int idx = blockIdx.x * 256 + threadIdx.x;
  const int j = idx & 127, k = idx >> 7;
  if (k >= d.K) return;
  const float v = d.src[(size_t)j * d.SW + k];
  const unsigned uh = __float_as_uint(v) & 0xffff0000u;
  const float lof = v - __uint_as_float(uh);
  // frag index: [ktile][jtile][lane=g*16+c][8]
  const int fo = ((((k >> 5) * 8 + (j >> 4)) * 64) + ((k >> 3) & 3) * 16 + (j & 15)) * 8 + (k & 7);
  d.hi[fo] = (unsigned short)(uh >> 16);
  d.lo[fo] = (unsigned short)(__float_as_uint(lof) >> 16);
}

extern "C" void kernel_launch(void* const* d_in, const int* in_sizes, int n_in,
                              void* d_out, int out_size, void* d_ws, size_t ws_size,
                              hipStream_t stream)
{
  const float* h_in  = (const float*)d_in[0];
  const float* x_in  = (const float*)d_in[1];
  const float* eattr = (const float*)d_in[2];
  const int*   eidx  = (const int*)d_in[3];
  const int N = in_sizes[0] / 128;
  const int E = in_sizes[2];

  const float* P[25];
  for (int i = 0; i < 25; ++i) P[i] = (const float*)d_in[4 + i];

  float* h_out = (float*)d_out;                     // [N,128]
  float* x_out = (float*)d_out + (size_t)N * 128;   // [N,3]

  // workspace carve
  float*    agg    = (float*)d_ws;                          // [N,128]
  unsigned* cnt    = (unsigned*)(agg + (size_t)N * 128);    // [N]
  unsigned* cursor = cnt + N;                               // [N]
  int*      sRowA  = (int*)(cursor + N);                    // [E]
  int*      sColA  = sRowA + E;                             // [E]
  float*    sRadA  = (float*)(sColA + E);                   // [E]
  float*    sEaA   = sRadA + E;                             // [E]
  float*    sCdA   = sEaA + E;                              // [E,3]
  unsigned short* hhi = (unsigned short*)(sCdA + (size_t)3 * E);  // [N,128]
  unsigned short* hlo = hhi + (size_t)N * 128;              // [N,128]
  unsigned short* wptr = hlo + (size_t)N * 128;

  WAll wa;
  auto addw = [&](int slot, const float* s, int K, int SW) {
    wa.m[slot].src = s; wa.m[slot].hi = wptr; wa.m[slot].lo = wptr + (size_t)K * 128;
    wa.m[slot].K = K; wa.m[slot].SW = SW;
    wptr += (size_t)2 * K * 128;
  };
  addw(0, P[0], 256, 258);  addw(1, P[2], 128, 128);   // g0 ew1, ew2
  addw(2, P[6], 256, 256);  addw(3, P[8], 128, 128);   // g0 nw1, nw2
  addw(4, P[10], 256, 258); addw(5, P[12], 128, 128);  // g1 ew1, ew2
  addw(6, P[16], 256, 256); addw(7, P[18], 128, 128);  // g1 nw1, nw2
  addw(8, P[20], 256, 258); addw(9, P[22], 128, 128);  // eq w1, w2

  unsigned short* Ca = wptr;                                // [N,128] bf16
  unsigned short* Cb = Ca + (size_t)N * 128;                // [N,128] bf16

  hipMemcpyAsync(h_out, h_in, (size_t)N * 128 * sizeof(float),
                 hipMemcpyDeviceToDevice, stream);
  hipMemcpyAsync(x_out, x_in, (size_t)N * 3 * sizeof(float),
                 hipMemcpyDeviceToDevice, stream);

  // sort edges by row; radial/coord_diff computed during scatter
  hipMemsetAsync(cnt, 0, (size_t)N * sizeof(unsigned), stream);
  hist_kernel<<<(E + 255) / 256, 256, 0, stream>>>(eidx, E, cnt);
  scan_kernel<<<1, 1024, 0, stream>>>(cnt, cursor, N);
  scatter_kernel<<<(E + 255) / 256, 256, 0, stream>>>(x_in, eidx, eattr, E,
      cursor, sRowA, sColA, sRadA, sEaA, sCdA);

  wprep_kernel<<<dim3(128, 10), 256, 0, stream>>>(wa);

  const int n4 = N * 32;                 // N*128/4
  const int sg = (n4 + 255) / 256;
  const int eg = (E + 255) / 256;        // 256 edges per block
  const int ng = (N + 127) / 128;

  split_kernel<<<sg, 256, 0, stream>>>(h_out, hhi, hlo, n4);

  for (int lyr = 0; lyr < 2; ++lyr) {
    const float* const* G = P + 10 * lyr;
    const WDesc* M = &wa.m[4 * lyr];
    dense2_kernel<<<ng, 256, 0, stream>>>(hhi, hlo, N, M[0].hi, M[0].lo, G[1], Ca, Cb);
    hipMemsetAsync(agg, 0, (size_t)N * 128 * sizeof(float), stream);
    edge_mfma<0><<<eg, 256, 0, stream>>>(Ca, Cb, sRowA, sColA, sRadA, sEaA, sCdA, E,
        G[0], M[1].hi, M[1].lo, G[3], G[4], G[5], agg);
    node_mfma<<<ng, 256, 0, stream>>>(h_out, hhi, hlo, hhi, hlo, agg, N,
        M[2].hi, M[2].lo, G[7], M[3].hi, M[3].lo, G[9]);
  }

  dense2_kernel<<<ng, 256, 0, stream>>>(hhi, hlo, N, wa.m[8].hi, wa.m[8].lo, P[21], Ca, Cb);
  edge_mfma<1><<<eg, 256, 0, stream>>>(Ca, Cb, sRowA, sColA, sRadA, sEaA, sCdA, E,
      P[20], wa.m[9].hi, wa.m[9].lo, P[23], P[24], nullptr, x_out);
}

// Round 9
// 2429.230 us; speedup vs baseline: 2.8752x; 2.8749x over previous
//
#include <hip/hip_runtime.h>
#include <cmath>

typedef short bfv8 __attribute__((ext_vector_type(8)));   // 8 bf16 as raw shorts
typedef float fv4  __attribute__((ext_vector_type(4)));

#define MFMA_B16(a,b,c) __builtin_amdgcn_mfma_f32_16x16x32_bf16((a),(b),(c),0,0,0)

// fast sigmoid/silu via v_exp_f32 / v_rcp_f32 (~1e-6 rel err)
__device__ __forceinline__ float fast_sigmoid(float x) {
  float e, r;
  asm("v_exp_f32 %0, %1" : "=v"(e) : "v"(-1.442695041f * x));
  const float d = 1.0f + e;
  asm("v_rcp_f32 %0, %1" : "=v"(r) : "v"(d));
  return r;
}
__device__ __forceinline__ float siluf(float x) { return x * fast_sigmoid(x); }

// pack split-bf16: low 16 = hi-part bf16, high 16 = lo-part bf16
__device__ __forceinline__ unsigned packsplit(float v) {
  unsigned uh = __float_as_uint(v) & 0xffff0000u;
  float lof = v - __uint_as_float(uh);
  return (uh >> 16) | (__float_as_uint(lof) & 0xffff0000u);
}

// ---------------------------------------------------------------------------
// Counting sort of edges by row (radial/coord_diff computed during scatter)
// ---------------------------------------------------------------------------
__global__ void hist_kernel(const int* __restrict__ eidx, int E,
                            unsigned* __restrict__ cnt)
{
  const int e = blockIdx.x * 256 + threadIdx.x;
  if (e < E) atomicAdd(&cnt[eidx[e]], 1u);
}

__global__ void scan_kernel(const unsigned* __restrict__ cnt,
                            unsigned* __restrict__ cursor, int N)
{
  __shared__ unsigned part[1024];
  const int t = threadIdx.x;
  const int chunk = (N + 1023) / 1024;
  const int base = t * chunk;
  unsigned s = 0;
  for (int i = 0; i < chunk; ++i) {
    const int idx = base + i;
    if (idx < N) s += cnt[idx];
  }
  part[t] = s;
  __syncthreads();
  for (int off = 1; off < 1024; off <<= 1) {
    unsigned v = 0;
    if (t >= off) v = part[t - off];
    __syncthreads();
    if (t >= off) part[t] += v;
    __syncthreads();
  }
  unsigned pre = (t == 0) ? 0u : part[t - 1];
  for (int i = 0; i < chunk; ++i) {
    const int idx = base + i;
    if (idx < N) { cursor[idx] = pre; pre += cnt[idx]; }
  }
}

__global__ void scatter_kernel(const float* __restrict__ x,
                               const int* __restrict__ eidx,
                               const float* __restrict__ eattr, int E,
                               unsigned* __restrict__ cursor,
                               int* __restrict__ sRowA, int* __restrict__ sColA,
                               float* __restrict__ sRadA, float* __restrict__ sEaA,
                               float* __restrict__ sCdA)
{
  const int e = blockIdx.x * 256 + threadIdx.x;
  if (e >= E) return;
  const int r = eidx[e], c = eidx[E + e];
  const float dx = x[(size_t)r * 3 + 0] - x[(size_t)c * 3 + 0];
  const float dy = x[(size_t)r * 3 + 1] - x[(size_t)c * 3 + 1];
  const float dz = x[(size_t)r * 3 + 2] - x[(size_t)c * 3 + 2];
  const float rad = dx * dx + dy * dy + dz * dz;
  const float inv = 1.0f / (sqrtf(rad + 1e-8f) + 1.0f);   // NORM_CONSTANT = 1
  const unsigned pos = atomicAdd(&cursor[r], 1u);
  sRowA[pos] = r;
  sColA[pos] = c;
  sRadA[pos] = rad;
  sEaA[pos]  = eattr[e];
  sCdA[(size_t)pos * 3 + 0] = dx * inv;
  sCdA[(size_t)pos * 3 + 1] = dy * inv;
  sCdA[(size_t)pos * 3 + 2] = dz * inv;
}

// ---------------------------------------------------------------------------
// CHAMPION edge pipeline (round-2-measured 525us form), fed sorted edges.
// Block: 256 thr = 4 waves; 128 edges/block; wave owns 32 rows x 128 cols.
// Fused GEMM1 (split-bf16, K=256) -> LDS transpose -> GEMM2 -> gate -> direct
// dense atomics. MODE 0 -> agg[N,128]; MODE 1 -> x_out[N,3] via coord_diff.
// ---------------------------------------------------------------------------
template <int MODE>
__global__ __launch_bounds__(256, 3)
void edge_mfma(const unsigned short* __restrict__ hhi,
               const unsigned short* __restrict__ hlo,
               const int* __restrict__ sRowA, const int* __restrict__ sColA,
               const float* __restrict__ sRadA, const float* __restrict__ sEaA,
               const float* __restrict__ sCdA, int E,
               const unsigned short* __restrict__ w1h, const unsigned short* __restrict__ w1l,
               const float* __restrict__ W1full, const float* __restrict__ b1,
               const unsigned short* __restrict__ w2h, const unsigned short* __restrict__ w2l,
               const float* __restrict__ b2,
               const float* __restrict__ awv, const float* __restrict__ abv,
               float* __restrict__ outbuf)
{
  __shared__ int   sRow[128], sCol[128];
  __shared__ float sRad[128], sEa[128];
  __shared__ __align__(16) unsigned sH[4][2048];   // per-wave 16x128 u32 (hi|lo)

  const int tid = threadIdx.x;
  const int w = tid >> 6, l = tid & 63;
  const int c16 = l & 15, g = l >> 4;
  const int e0 = blockIdx.x * 128;

  if (tid < 128) {
    const int e = min(e0 + tid, E - 1);
    sRow[tid] = sRowA[e];
    sCol[tid] = sColA[e];
    sRad[tid] = sRadA[e];
    sEa[tid]  = sEaA[e];
  }
  __syncthreads();

  const int rw = w * 32;
  int nidA[2], nidB[2];
#pragma unroll
  for (int rt = 0; rt < 2; ++rt) {
    nidA[rt] = sRow[rw + rt * 16 + c16];
    nidB[rt] = sCol[rw + rt * 16 + c16];
  }

  fv4 acc[2][8];
#pragma unroll
  for (int a = 0; a < 2; ++a)
#pragma unroll
    for (int b = 0; b < 8; ++b) acc[a][b] = (fv4)0.0f;

  // ---- GEMM1: [32 x 256] x W1^T (k 0..127 = h[row], 128..255 = h[col]) ----
#pragma unroll 2
  for (int kc = 0; kc < 8; ++kc) {
    bfv8 Ah[2], Al[2];
    const int kh = (kc & 3) * 32 + g * 8;
#pragma unroll
    for (int rt = 0; rt < 2; ++rt) {
      const int nid = (kc < 4) ? nidA[rt] : nidB[rt];
      const size_t off = (size_t)nid * 128 + kh;
      Ah[rt] = *(const bfv8*)(hhi + off);
      Al[rt] = *(const bfv8*)(hlo + off);
    }
#pragma unroll
    for (int jt = 0; jt < 8; ++jt) {
      const size_t bo = ((size_t)(kc * 8 + jt) * 64 + l) * 8;
      bfv8 Bh = *(const bfv8*)(w1h + bo);
      bfv8 Bl = *(const bfv8*)(w1l + bo);
#pragma unroll
      for (int rt = 0; rt < 2; ++rt) {
        acc[rt][jt] = MFMA_B16(Ah[rt], Bh, acc[rt][jt]);
        acc[rt][jt] = MFMA_B16(Al[rt], Bh, acc[rt][jt]);
        acc[rt][jt] = MFMA_B16(Ah[rt], Bl, acc[rt][jt]);
      }
    }
  }

  unsigned* sHW = sH[w];
  const float ab0 = (MODE == 0) ? abv[0] : 0.0f;

#pragma unroll 1
  for (int rt = 0; rt < 2; ++rt) {
    // ---- epilogue1: tail cols (radial, ea) + bias + silu -> sH (swizzled) ----
#pragma unroll
    for (int jt = 0; jt < 8; ++jt) {
      const int col = jt * 16 + c16;
      const float wt0 = W1full[(size_t)col * 258 + 256];
      const float wt1 = W1full[(size_t)col * 258 + 257];
      const float bb  = b1[col];
#pragma unroll
      for (int reg = 0; reg < 4; ++reg) {
        const int rr = 4 * g + reg;
        const int er = rw + rt * 16 + rr;
        const float v = acc[rt][jt][reg] + sRad[er] * wt0 + sEa[er] * wt1 + bb;
        sHW[rr * 128 + (col ^ ((rr & 7) << 2))] = packsplit(siluf(v));
      }
    }

    // ---- GEMM2: silu(H1)[16x128] x W2^T ----
    fv4 accB[8];
#pragma unroll
    for (int jt = 0; jt < 8; ++jt) accB[jt] = (fv4)0.0f;
    const int sxz = (c16 & 7) << 2;
#pragma unroll 2
    for (int kc2 = 0; kc2 < 4; ++kc2) {
      const int k0 = kc2 * 32 + g * 8;
      const int i1 = c16 * 128 + (k0 ^ sxz);
      const int4 q0 = *((const int4*)(sHW + i1));
      const int4 q1 = *((const int4*)(sHW + (i1 ^ 4)));
      bfv8 Ah2, Al2;
      {
        const int qq[8] = {q0.x, q0.y, q0.z, q0.w, q1.x, q1.y, q1.z, q1.w};
#pragma unroll
        for (int i = 0; i < 8; ++i) {
          Ah2[i] = (short)(((unsigned)qq[i]) & 0xffffu);
          Al2[i] = (short)(((unsigned)qq[i]) >> 16);
        }
      }
#pragma unroll
      for (int jt = 0; jt < 8; ++jt) {
        const size_t bo = ((size_t)(kc2 * 8 + jt) * 64 + l) * 8;
        bfv8 Bh = *(const bfv8*)(w2h + bo);
        bfv8 Bl = *(const bfv8*)(w2l + bo);
        accB[jt] = MFMA_B16(Ah2, Bh, accB[jt]);
        accB[jt] = MFMA_B16(Al2, Bh, accB[jt]);
        accB[jt] = MFMA_B16(Ah2, Bl, accB[jt]);
      }
    }

    // ---- epilogue2 ----
    float p[4] = {0.f, 0.f, 0.f, 0.f};
#pragma unroll
    for (int jt = 0; jt < 8; ++jt) {
      const int col = jt * 16 + c16;
      const float bb = b2[col], aa = awv[col];
#pragma unroll
      for (int reg = 0; reg < 4; ++reg) {
        const float m = siluf(accB[jt][reg] + bb);
        accB[jt][reg] = m;
        p[reg] += m * aa;
      }
    }
#pragma unroll
    for (int msk = 1; msk < 16; msk <<= 1) {
#pragma unroll
      for (int reg = 0; reg < 4; ++reg) p[reg] += __shfl_xor(p[reg], msk, 64);
    }

    if constexpr (MODE == 0) {
#pragma unroll
      for (int reg = 0; reg < 4; ++reg) {
        const int er = rw + rt * 16 + 4 * g + reg;
        if (e0 + er < E) {
          const float att = fast_sigmoid(p[reg] + ab0);
          float* dst = outbuf + (size_t)sRow[er] * 128;
#pragma unroll
          for (int jt = 0; jt < 8; ++jt)
            unsafeAtomicAdd(dst + jt * 16 + c16, accB[jt][reg] * att);
        }
      }
    } else {
      if (c16 == 0) {
#pragma unroll
        for (int reg = 0; reg < 4; ++reg) {
          const int er = rw + rt * 16 + 4 * g + reg;
          const int e = e0 + er;
          if (e < E) {
            const float s = p[reg] * 0.01f;          // / NORM_FACTOR
            float* dst = outbuf + (size_t)sRow[er] * 3;
            unsafeAtomicAdd(dst + 0, sCdA[(size_t)e * 3 + 0] * s);
            unsafeAtomicAdd(dst + 1, sCdA[(size_t)e * 3 + 1] * s);
            unsafeAtomicAdd(dst + 2, sCdA[(size_t)e * 3 + 2] * s);
          }
        }
      }
    }
  }
}

// ---------------------------------------------------------------------------
// Node model (MFMA): msg = silu([h, agg/100] W1^T + b1) W2^T + b2; h += msg
// Emits updated split-bf16 planes (fused split).
// ---------------------------------------------------------------------------
__global__ __launch_bounds__(256, 3)
void node_mfma(float* __restrict__ hio,
               const unsigned short* __restrict__ hhi,
               const unsigned short* __restrict__ hlo,
               unsigned short* __restrict__ ohi,
               unsigned short* __restrict__ olo,
               const float* __restrict__ agg, int N,
               const unsigned short* __restrict__ w1h, const unsigned short* __restrict__ w1l,
               const float* __restrict__ b1,
               const unsigned short* __restrict__ w2h, const unsigned short* __restrict__ w2l,
               const float* __restrict__ b2)
{
  __shared__ __align__(16) unsigned sH[4][2048];

  const int tid = threadIdx.x;
  const int w = tid >> 6, l = tid & 63;
  const int c16 = l & 15, g = l >> 4;
  const int n0 = blockIdx.x * 128;
  const int rw = w * 32;

  int rowA[2];
#pragma unroll
  for (int rt = 0; rt < 2; ++rt) rowA[rt] = min(n0 + rw + rt * 16 + c16, N - 1);

  fv4 acc[2][8];
#pragma unroll
  for (int a = 0; a < 2; ++a)
#pragma unroll
    for (int b = 0; b < 8; ++b) acc[a][b] = (fv4)0.0f;

#pragma unroll 2
  for (int kc = 0; kc < 8; ++kc) {
    bfv8 Ah[2], Al[2];
    if (kc < 4) {
      const int kh = kc * 32 + g * 8;
#pragma unroll
      for (int rt = 0; rt < 2; ++rt) {
        const size_t off = (size_t)rowA[rt] * 128 + kh;
        Ah[rt] = *(const bfv8*)(hhi + off);
        Al[rt] = *(const bfv8*)(hlo + off);
      }
    } else {
      const int kh = (kc - 4) * 32 + g * 8;
#pragma unroll
      for (int rt = 0; rt < 2; ++rt) {
        const float4 v0 = *(const float4*)(agg + (size_t)rowA[rt] * 128 + kh);
        const float4 v1 = *(const float4*)(agg + (size_t)rowA[rt] * 128 + kh + 4);
        const float vv[8] = {v0.x, v0.y, v0.z, v0.w, v1.x, v1.y, v1.z, v1.w};
#pragma unroll
        for (int i = 0; i < 8; ++i) {
          const float xs = vv[i] * 0.01f;            // agg / normalization_factor
          const unsigned uh = __float_as_uint(xs) & 0xffff0000u;
          Ah[rt][i] = (short)(uh >> 16);
          const float lof = xs - __uint_as_float(uh);
          Al[rt][i] = (short)(__float_as_uint(lof) >> 16);
        }
      }
    }
#pragma unroll
    for (int jt = 0; jt < 8; ++jt) {
      const size_t bo = ((size_t)(kc * 8 + jt) * 64 + l) * 8;
      bfv8 Bh = *(const bfv8*)(w1h + bo);
      bfv8 Bl = *(const bfv8*)(w1l + bo);
#pragma unroll
      for (int rt = 0; rt < 2; ++rt) {
        acc[rt][jt] = MFMA_B16(Ah[rt], Bh, acc[rt][jt]);
        acc[rt][jt] = MFMA_B16(Al[rt], Bh, acc[rt][jt]);
        acc[rt][jt] = MFMA_B16(Ah[rt], Bl, acc[rt][jt]);
      }
    }
  }

  unsigned* sHW = sH[w];
#pragma unroll 1
  for (int rt = 0; rt < 2; ++rt) {
#pragma unroll
    for (int jt = 0; jt < 8; ++jt) {
      const int col = jt * 16 + c16;
      const float bb = b1[col];
#pragma unroll
      for (int reg = 0; reg < 4; ++reg) {
        const int rr = 4 * g + reg;
        sHW[rr * 128 + (col ^ ((rr & 7) << 2))] = packsplit(siluf(acc[rt][jt][reg] + bb));
      }
    }

    fv4 accB[8];
#pragma unroll
    for (int jt = 0; jt < 8; ++jt) accB[jt] = (fv4)0.0f;
    const int sxz = (c16 & 7) << 2;
#pragma unroll 2
    for (int kc2 = 0; kc2 < 4; ++kc2) {
      const int k0 = kc2 * 32 + g * 8;
      const int i1 = c16 * 128 + (k0 ^ sxz);
      const int4 q0 = *((const int4*)(sHW + i1));
      const int4 q1 = *((const int4*)(sHW + (i1 ^ 4)));
      bfv8 Ah2, Al2;
      {
        const int qq[8] = {q0.x, q0.y, q0.z, q0.w, q1.x, q1.y, q1.z, q1.w};
#pragma unroll
        for (int i = 0; i < 8; ++i) {
          Ah2[i] = (short)(((unsigned)qq[i]) & 0xffffu);
          Al2[i] = (short)(((unsigned)qq[i]) >> 16);
        }
      }
#pragma unroll
      for (int jt = 0; jt < 8; ++jt) {
        const size_t bo = ((size_t)(kc2 * 8 + jt) * 64 + l) * 8;
        bfv8 Bh = *(const bfv8*)(w2h + bo);
        bfv8 Bl = *(const bfv8*)(w2l + bo);
        accB[jt] = MFMA_B16(Ah2, Bh, accB[jt]);
        accB[jt] = MFMA_B16(Al2, Bh, accB[jt]);
        accB[jt] = MFMA_B16(Ah2, Bl, accB[jt]);
      }
    }

#pragma unroll
    for (int reg = 0; reg < 4; ++reg) {
      const int n = n0 + rw + rt * 16 + 4 * g + reg;
      if (n < N) {
        float* hp = hio + (size_t)n * 128;
#pragma unroll
        for (int jt = 0; jt < 8; ++jt) {
          const int col = jt * 16 + c16;
          const float nv = hp[col] + accB[jt][reg] + b2[col];   // residual add
          hp[col] = nv;
          const unsigned ps = packsplit(nv);
          ohi[(size_t)n * 128 + col] = (unsigned short)(ps & 0xffffu);
          olo[(size_t)n * 128 + col] = (unsigned short)(ps >> 16);
        }
      }
    }
  }
}

// split fp32 -> bf16 hi/lo planes — initial h only
__global__ void split_kernel(const float* __restrict__ src,
                             unsigned short* __restrict__ hi,
                             unsigned short* __restrict__ lo, int n4)
{
  const int i = blockIdx.x * 256 + threadIdx.x;
  if (i >= n4) return;
  const float4 v = ((const float4*)src)[i];
  const float vv[4] = {v.x, v.y, v.z, v.w};
  ushort4 ho, lq;
  unsigned short* hp = (unsigned short*)&ho;
  unsigned short* lp = (unsigned short*)&lq;
#pragma unroll
  for (int k = 0; k < 4; ++k) {
    const unsigned uh = __float_as_uint(vv[k]) & 0xffff0000u;
    hp[k] = (unsigned short)(uh >> 16);
    const float lof = vv[k] - __uint_as_float(uh);
    lp[k] = (unsigned short)(__float_as_uint(lof) >> 16);
  }
  ((ushort4*)hi)[i] = ho;
  ((ushort4*)lo)[i] = lq;
}

// weight prep: W[j][k] (row-major, stride SW) -> MFMA B-frag layout hi/lo planes
struct WDesc { const float* src; unsigned short* hi; unsigned short* lo; int K; int SW; };
struct WAll { WDesc m[10]; };

__global__ void wprep_kernel(WAll wa)
{
  const WDesc d = wa.m[blockIdx.y];
  const int idx = blockIdx.x * 256 + threadIdx.x;
  const int j = idx & 127, k = idx >> 7;
  if (k >= d.K) return;
  const float v = d.src[(size_t)j * d.SW + k];
  const unsigned uh = __float_as_uint(v) & 0xffff0000u;
  const float lof = v - __uint_as_float(uh);
  // frag index: [ktile][jtile][lane=g*16+c][8]
  const int fo = ((((k >> 5) * 8 + (j >> 4)) * 64) + ((k >> 3) & 3) * 16 + (j & 15)) * 8 + (k & 7);
  d.hi[fo] = (unsigned short)(uh >> 16);
  d.lo[fo] = (unsigned short)(__float_as_uint(lof) >> 16);
}

extern "C" void kernel_launch(void* const* d_in, const int* in_sizes, int n_in,
                              void* d_out, int out_size, void* d_ws, size_t ws_size,
                              hipStream_t stream)
{
  const float* h_in  = (const float*)d_in[0];
  const float* x_in  = (const float*)d_in[1];
  const float* eattr = (const float*)d_in[2];
  const int*   eidx  = (const int*)d_in[3];
  const int N = in_sizes[0] / 128;
  const int E = in_sizes[2];

  const float* P[25];
  for (int i = 0; i < 25; ++i) P[i] = (const float*)d_in[4 + i];

  float* h_out = (float*)d_out;                     // [N,128]
  float* x_out = (float*)d_out + (size_t)N * 128;   // [N,3]

  // workspace carve
  float*    agg    = (float*)d_ws;                          // [N,128]
  unsigned* cnt    = (unsigned*)(agg + (size_t)N * 128);    // [N]
  unsigned* cursor = cnt + N;                               // [N]
  int*      sRowA  = (int*)(cursor + N);                    // [E]
  int*      sColA  = sRowA + E;                             // [E]
  float*    sRadA  = (float*)(sColA + E);                   // [E]
  float*    sEaA   = sRadA + E;                             // [E]
  float*    sCdA   = sEaA + E;                              // [E,3]
  unsigned short* hhi = (unsigned short*)(sCdA + (size_t)3 * E);  // [N,128]
  unsigned short* hlo = hhi + (size_t)N * 128;              // [N,128]
  unsigned short* wptr = hlo + (size_t)N * 128;

  WAll wa;
  auto addw = [&](int slot, const float* s, int K, int SW) {
    wa.m[slot].src = s; wa.m[slot].hi = wptr; wa.m[slot].lo = wptr + (size_t)K * 128;
    wa.m[slot].K = K; wa.m[slot].SW = SW;
    wptr += (size_t)2 * K * 128;
  };
  addw(0, P[0], 256, 258);  addw(1, P[2], 128, 128);   // g0 ew1, ew2
  addw(2, P[6], 256, 256);  addw(3, P[8], 128, 128);   // g0 nw1, nw2
  addw(4, P[10], 256, 258); addw(5, P[12], 128, 128);  // g1 ew1, ew2
  addw(6, P[16], 256, 256); addw(7, P[18], 128, 128);  // g1 nw1, nw2
  addw(8, P[20], 256, 258); addw(9, P[22], 128, 128);  // eq w1, w2

  hipMemcpyAsync(h_out, h_in, (size_t)N * 128 * sizeof(float),
                 hipMemcpyDeviceToDevice, stream);
  hipMemcpyAsync(x_out, x_in, (size_t)N * 3 * sizeof(float),
                 hipMemcpyDeviceToDevice, stream);

  // sort edges by row; radial/coord_diff computed during scatter
  hipMemsetAsync(cnt, 0, (size_t)N * sizeof(unsigned), stream);
  hist_kernel<<<(E + 255) / 256, 256, 0, stream>>>(eidx, E, cnt);
  scan_kernel<<<1, 1024, 0, stream>>>(cnt, cursor, N);
  scatter_kernel<<<(E + 255) / 256, 256, 0, stream>>>(x_in, eidx, eattr, E,
      cursor, sRowA, sColA, sRadA, sEaA, sCdA);

  wprep_kernel<<<dim3(128, 10), 256, 0, stream>>>(wa);

  const int n4 = N * 32;                 // N*128/4
  const int sg = (n4 + 255) / 256;
  const int eg = (E + 127) / 128;        // 128 edges per block (champion tile)
  const int ng = (N + 127) / 128;

  split_kernel<<<sg, 256, 0, stream>>>(h_out, hhi, hlo, n4);

  for (int lyr = 0; lyr < 2; ++lyr) {
    const float* const* G = P + 10 * lyr;
    const WDesc* M = &wa.m[4 * lyr];
    hipMemsetAsync(agg, 0, (size_t)N * 128 * sizeof(float), stream);
    edge_mfma<0><<<eg, 256, 0, stream>>>(hhi, hlo, sRowA, sColA, sRadA, sEaA, sCdA, E,
        M[0].hi, M[0].lo, G[0], G[1], M[1].hi, M[1].lo, G[3],
        G[4], G[5], agg);
    node_mfma<<<ng, 256, 0, stream>>>(h_out, hhi, hlo, hhi, hlo, agg, N,
        M[2].hi, M[2].lo, G[7], M[3].hi, M[3].lo, G[9]);
  }

  edge_mfma<1><<<eg, 256, 0, stream>>>(hhi, hlo, sRowA, sColA, sRadA, sEaA, sCdA, E,
      wa.m[8].hi, wa.m[8].lo, P[20], P[21], wa.m[9].hi, wa.m[9].lo, P[23],
      P[24], nullptr, x_out);
}